// Round 5
// baseline (100.302 us; speedup 1.0000x reference)
//
#include <hip/hip_runtime.h>
#include <math.h>

#define NB 32
#define NN 4096
#define NK 16
#define ND 128
#define KPT 4            // k's per thread
#define NKG (NK/KPT)     // 4 k-groups
#define NCHUNK 16        // 256-point chunks per batch
#define NBLK (NB*NCHUNK*NKG)   // 2048 blocks

#define W_STD 0.01f
#define W_REC 1.0
#define W_SPS 0.1
#define W_EXT 0.01
#define W_KLD 0.001
#define W_CST 0.1

__device__ __forceinline__ float flog2(float x) { return __builtin_amdgcn_logf(x); }
__device__ __forceinline__ float fexp2(float x) { return __builtin_amdgcn_exp2f(x); }
__device__ __forceinline__ float frsq (float x) { return __builtin_amdgcn_rsqf(x); }

// block = (b, chunk, kg): 256 threads = 256 points, each doing 4 k's.
// Per-(b,kg) params are block-uniform -> compiler lowers to s_load (SGPRs),
// no LDS staging, no param __syncthreads.
__global__ __launch_bounds__(256) void rec_kernel(
    const float* __restrict__ pc, const float* __restrict__ normals,
    const float* __restrict__ rnd, const float* __restrict__ scale,
    const float* __restrict__ shapes, const float* __restrict__ rotate,
    const float* __restrict__ mean, const float* __restrict__ assign,
    float* __restrict__ recpart, float* __restrict__ colpart)
{
    const int bid   = blockIdx.x;
    const int b     = bid >> 6;
    const int chunk = (bid >> 2) & 15;
    const int kg    = bid & 3;
    const int t     = threadIdx.x;
    const int n     = chunk * 256 + t;

    const float* __restrict__ Rb = rotate + b*144 + kg*36;
    const float* __restrict__ Sb = scale  + b*48  + kg*12;
    const float* __restrict__ Eb = shapes + b*32  + kg*8;
    const float* __restrict__ Mb = mean   + b*48  + kg*12;

    __shared__ float csum[4][KPT];
    __shared__ float wsum[4];

    const long pbase = (long)(b*NN + n);
    const float px = pc[pbase*3+0], py = pc[pbase*3+1], pz = pc[pbase*3+2];
    const float nx = normals[pbase*3+0], ny = normals[pbase*3+1], nz = normals[pbase*3+2];

    const float nn2 = nx*nx + ny*ny + nz*nz;
    const float inn = frsq(nn2);
    const float ux = nx*inn, uy = ny*inn, uz = nz*inn;       // unit normal
    const float c_n = rnd[pbase] * W_STD * (nn2 * inn);      // noise * ||n||

    const float4 av = *(const float4*)(assign + pbase*16 + kg*4);
    float a[KPT] = {av.x, av.y, av.z, av.w};

    const int wave = t >> 6, lane = t & 63;
    float rec = 0.f;

    #pragma unroll
    for (int kk = 0; kk < KPT; ++kk) {
        const float R0 = Rb[kk*9+0], R1 = Rb[kk*9+1], R2 = Rb[kk*9+2];
        const float R3 = Rb[kk*9+3], R4 = Rb[kk*9+4], R5 = Rb[kk*9+5];
        const float R6 = Rb[kk*9+6], R7 = Rb[kk*9+7], R8 = Rb[kk*9+8];
        const float cx = Mb[kk*3], cy = Mb[kk*3+1], cz = Mb[kk*3+2];
        const float s0 = Sb[kk*3], s1 = Sb[kk*3+1], s2 = Sb[kk*3+2];
        const float e0 = Eb[kk*2], e1 = Eb[kk*2+1];

        // pci = R^T (pc - mean)
        const float dx0 = px-cx, dy0 = py-cy, dz0 = pz-cz;
        const float pcx = R0*dx0 + R3*dy0 + R6*dz0;
        const float pcy = R1*dx0 + R4*dy0 + R7*dz0;
        const float pcz = R2*dx0 + R5*dy0 + R8*dz0;
        // ni = R^T unit_normal
        const float nix = R0*ux + R3*uy + R6*uz;
        const float niy = R1*ux + R4*uy + R7*uz;
        const float niz = R2*ux + R5*uy + R8*uz;
        // psi = pci + (noise*||n||) * ni
        const float psx = fmaf(c_n, nix, pcx);
        const float psy = fmaf(c_n, niy, pcy);
        const float psz = fmaf(c_n, niz, pcz);

        // argmax over [-nix, nix, -niy, niy, -niz, niz], first-max wins
        float best = -nix; int idx = 0;
        if ( nix > best) { best =  nix; idx = 1; }
        if (-niy > best) { best = -niy; idx = 2; }
        if ( niy > best) { best =  niy; idx = 3; }
        if (-niz > best) { best = -niz; idx = 4; }
        if ( niz > best) { best =  niz; idx = 5; }

        float sx = fminf(fmaxf(psx, -s0), s0);
        float sy = fminf(fmaxf(psy, -s1), s1);
        float sz = fminf(fmaxf(psz, -s2), s2);
        const float sgn = (idx & 1) ? 1.f : -1.f;
        const int axis = idx >> 1;
        if (axis == 0)      sx = sgn*s0;
        else if (axis == 1) sy = sgn*s1;
        else                sz = sgn*s2;

        // log2-space superquadric point:
        //   X = copysign(s0 * cphi^e0 * |ct|^e1, sx), etc.
        const float hx  = sx*sx + sy*sy;
        const float r3  = hx + sz*sz;          // >= min(scale)^2 >= 0.01
        const float Lhx = flog2(hx);
        const float Lr3 = flog2(r3);
        const float Lx  = flog2(fabsf(sx));
        const float Ly  = flog2(fabsf(sy));
        const float Lz  = flog2(fabsf(sz));

        const float e0Lc = e0 * (0.5f*(Lhx - Lr3));
        const float aX = fmaf(e1, fmaf(-0.5f, Lhx, Lx), e0Lc);
        const float aY = fmaf(e1, fmaf(-0.5f, Lhx, Ly), e0Lc);
        const float aZ = e0 * fmaf(-0.5f, Lr3, Lz);

        const float X = copysignf(s0 * fexp2(aX), sx);
        const float Y = copysignf(s1 * fexp2(aY), sy);
        const float Z = copysignf(s2 * fexp2(aZ), sz);

        const float ddx = X-pcx, ddy = Y-pcy, ddz = Z-pcz;
        rec = fmaf(ddx*ddx + ddy*ddy + ddz*ddz, a[kk], rec);
    }

    // block-reduce rec (wave butterfly then cross-wave)
    #pragma unroll
    for (int o = 32; o; o >>= 1) rec += __shfl_xor(rec, o);
    if (lane == 0) wsum[wave] = rec;

    // column-sum partials for this block's 4 k's
    #pragma unroll
    for (int kk = 0; kk < KPT; ++kk) {
        float v = a[kk];
        #pragma unroll
        for (int o = 32; o; o >>= 1) v += __shfl_xor(v, o);
        if (lane == 0) csum[wave][kk] = v;
    }
    __syncthreads();
    if (t == 0) recpart[bid] = wsum[0] + wsum[1] + wsum[2] + wsum[3];
    if (t < KPT) colpart[bid*KPT + t] = csum[0][t] + csum[1][t] + csum[2][t] + csum[3][t];
}

// Single block: column sums -> SPS/EXT; KLD; CST; REC sum; weighted combine.
__global__ __launch_bounds__(256) void finalize_kernel(
    const float* __restrict__ exist, const float* __restrict__ mu,
    const float* __restrict__ logvar, const float* __restrict__ mean,
    const float* __restrict__ trans, const float* __restrict__ recpart,
    const float* __restrict__ colpart, float* __restrict__ out)
{
    const int t = threadIdx.x;
    __shared__ float scol[NB*NK];
    __shared__ double red[256];

    // colsum[b][k] = sum over 16 chunks
    for (int i = t; i < NB*NK; i += 256) {
        int b = i >> 4, k = i & 15;
        float s = 0.f;
        #pragma unroll
        for (int c = 0; c < NCHUNK; ++c)
            s += colpart[(((b*NCHUNK + c)*NKG) + (k >> 2))*KPT + (k & 3)];
        scol[i] = s;
    }
    __syncthreads();

    double acc = 0.0;

    // KLD: native exp2 (e^x = 2^(x*log2e))
    for (int i = t; i < NB*ND; i += 256) {
        float lv = logvar[i], m = mu[i];
        float elv = fexp2(lv * 1.44269504f);
        acc += (double)(-0.5f * (1.0f + lv - m*m - elv)) * (W_KLD / (double)NB);
    }

    // EXT + CST over 512 (b,k) slots
    for (int i = t; i < NB*NK; i += 256) {
        float l  = exist[i];
        float gt = (scol[i] > 24.0f) ? 1.0f : 0.0f;
        float u  = fexp2(-fabsf(l) * 1.44269504f);        // exp(-|l|) in (0,1]
        float lg = flog2(1.0f + u) * 0.69314718f;         // log1p(u)
        float ext = fmaxf(l, 0.f) - l*gt + lg;
        acc += (double)ext * (W_EXT / (double)(NB*NK));

        float dx = mean[i*3+0] - trans[i*3+0];
        float dy = mean[i*3+1] - trans[i*3+1];
        float dz = mean[i*3+2] - trans[i*3+2];
        acc += (double)sqrtf(dx*dx + dy*dy + dz*dz) * (W_CST / (double)(NB*NK));
    }

    // REC over 2048 block partials
    for (int i = t; i < NBLK; i += 256)
        acc += (double)recpart[i] * (W_REC / ((double)NB * (double)NN));

    // SPS
    if (t < NB) {
        float sm = 0.f;
        #pragma unroll
        for (int k = 0; k < NK; ++k)
            sm += sqrtf(scol[t*NK + k] * (1.0f/(float)NN) + 0.01f);
        sm *= (1.0f/(float)NK);
        acc += (double)(sm*sm) * (W_SPS / (double)NB);
    }

    red[t] = acc;
    __syncthreads();
    for (int s2 = 128; s2; s2 >>= 1) {
        if (t < s2) red[t] += red[t + s2];
        __syncthreads();
    }
    if (t == 0) out[0] = (float)red[0];
}

extern "C" void kernel_launch(void* const* d_in, const int* in_sizes, int n_in,
                              void* d_out, int out_size, void* d_ws, size_t ws_size,
                              hipStream_t stream) {
    const float* pc      = (const float*)d_in[0];
    const float* normals = (const float*)d_in[1];
    const float* rnd     = (const float*)d_in[2];
    const float* scale   = (const float*)d_in[3];
    const float* shapes  = (const float*)d_in[4];
    const float* rotate  = (const float*)d_in[5];
    const float* mean    = (const float*)d_in[6];
    const float* assign  = (const float*)d_in[7];
    const float* exist   = (const float*)d_in[8];
    const float* mu      = (const float*)d_in[9];
    const float* logvar  = (const float*)d_in[10];
    const float* trans   = (const float*)d_in[11];

    float* recpart = (float*)d_ws;            // NBLK floats, all written each call
    float* colpart = recpart + NBLK;          // NBLK*KPT floats, all written each call

    rec_kernel<<<dim3(NBLK), dim3(256), 0, stream>>>(
        pc, normals, rnd, scale, shapes, rotate, mean, assign, recpart, colpart);
    finalize_kernel<<<dim3(1), dim3(256), 0, stream>>>(
        exist, mu, logvar, mean, trans, recpart, colpart, (float*)d_out);
}

// Round 7
// 98.541 us; speedup vs baseline: 1.0179x; 1.0179x over previous
//
#include <hip/hip_runtime.h>
#include <math.h>

#define NB 32
#define NN 4096
#define NK 16
#define ND 128
#define KPT 4            // k's per thread
#define NKG (NK/KPT)     // 4 k-groups
#define NPT 2            // points per thread
#define NCHUNK 8         // 512-point chunks per batch
#define NBLK (NB*NCHUNK*NKG)   // 1024 blocks

#define W_STD 0.01f
#define W_REC 1.0
#define W_SPS 0.1
#define W_EXT 0.01
#define W_KLD 0.001
#define W_CST 0.1

__device__ __forceinline__ float flog2(float x) { return __builtin_amdgcn_logf(x); }
__device__ __forceinline__ float fexp2(float x) { return __builtin_amdgcn_exp2f(x); }
__device__ __forceinline__ float frsq (float x) { return __builtin_amdgcn_rsqf(x); }

// block = (b, chunk, kg): 256 threads x 2 points, each doing 4 k's.
// Params are block-uniform -> SGPR via s_load; two independent per-point
// dependency chains per thread for latency hiding.
__global__ __launch_bounds__(256, 4) void rec_kernel(
    const float* __restrict__ pc, const float* __restrict__ normals,
    const float* __restrict__ rnd, const float* __restrict__ scale,
    const float* __restrict__ shapes, const float* __restrict__ rotate,
    const float* __restrict__ mean, const float* __restrict__ assign,
    float* __restrict__ recpart, float* __restrict__ colpart)
{
    const int bid   = blockIdx.x;
    const int b     = bid >> 5;
    const int chunk = (bid >> 2) & 7;
    const int kg    = bid & 3;
    const int t     = threadIdx.x;

    const float* __restrict__ Rb = rotate + b*144 + kg*36;
    const float* __restrict__ Sb = scale  + b*48  + kg*12;
    const float* __restrict__ Eb = shapes + b*32  + kg*8;
    const float* __restrict__ Mb = mean   + b*48  + kg*12;

    __shared__ float csum[4][KPT];
    __shared__ float wsum[4];

    const long pA = (long)(b*NN + chunk*512 + t);
    const long pB = pA + 256;

    const float pxA = pc[pA*3+0], pyA = pc[pA*3+1], pzA = pc[pA*3+2];
    const float pxB = pc[pB*3+0], pyB = pc[pB*3+1], pzB = pc[pB*3+2];
    const float nxA = normals[pA*3+0], nyA = normals[pA*3+1], nzA = normals[pA*3+2];
    const float nxB = normals[pB*3+0], nyB = normals[pB*3+1], nzB = normals[pB*3+2];

    const float nn2A = nxA*nxA + nyA*nyA + nzA*nzA;
    const float nn2B = nxB*nxB + nyB*nyB + nzB*nzB;
    const float innA = frsq(nn2A), innB = frsq(nn2B);
    const float uxA = nxA*innA, uyA = nyA*innA, uzA = nzA*innA;
    const float uxB = nxB*innB, uyB = nyB*innB, uzB = nzB*innB;
    const float cnA = rnd[pA] * W_STD * (nn2A * innA);
    const float cnB = rnd[pB] * W_STD * (nn2B * innB);

    const float4 avA = *(const float4*)(assign + pA*16 + kg*4);
    const float4 avB = *(const float4*)(assign + pB*16 + kg*4);
    const float aA[KPT] = {avA.x, avA.y, avA.z, avA.w};
    const float aB[KPT] = {avB.x, avB.y, avB.z, avB.w};

    const int wave = t >> 6, lane = t & 63;
    float recA = 0.f, recB = 0.f;

    #pragma unroll
    for (int kk = 0; kk < KPT; ++kk) {
        const float R0 = Rb[kk*9+0], R1 = Rb[kk*9+1], R2 = Rb[kk*9+2];
        const float R3 = Rb[kk*9+3], R4 = Rb[kk*9+4], R5 = Rb[kk*9+5];
        const float R6 = Rb[kk*9+6], R7 = Rb[kk*9+7], R8 = Rb[kk*9+8];
        const float cx = Mb[kk*3], cy = Mb[kk*3+1], cz = Mb[kk*3+2];
        const float s0 = Sb[kk*3], s1 = Sb[kk*3+1], s2 = Sb[kk*3+2];
        const float e0 = Eb[kk*2], e1 = Eb[kk*2+1];

        #pragma unroll
        for (int p = 0; p < NPT; ++p) {
            const float px = p ? pxB : pxA, py = p ? pyB : pyA, pz = p ? pzB : pzA;
            const float ux = p ? uxB : uxA, uy = p ? uyB : uyA, uz = p ? uzB : uzA;
            const float c_n = p ? cnB : cnA;
            const float ak  = p ? aB[kk] : aA[kk];

            // pci = R^T (pc - mean)
            const float dx0 = px-cx, dy0 = py-cy, dz0 = pz-cz;
            const float pcx = R0*dx0 + R3*dy0 + R6*dz0;
            const float pcy = R1*dx0 + R4*dy0 + R7*dz0;
            const float pcz = R2*dx0 + R5*dy0 + R8*dz0;
            // ni = R^T unit_normal
            const float nix = R0*ux + R3*uy + R6*uz;
            const float niy = R1*ux + R4*uy + R7*uz;
            const float niz = R2*ux + R5*uy + R8*uz;
            // psi = pci + (noise*||n||) * ni
            const float psx = fmaf(c_n, nix, pcx);
            const float psy = fmaf(c_n, niy, pcy);
            const float psz = fmaf(c_n, niz, pcz);

            // argmax over [-nix,nix,-niy,niy,-niz,niz], first-max-wins:
            // axis = first axis with max |ni|; sign = (ni_axis > 0)
            const float ax = fabsf(nix), ay = fabsf(niy), az = fabsf(niz);
            const bool isX = (ax >= ay) && (ax >= az);
            const bool isY = (!isX) && (ay >= az);
            const bool isZ = (!isX) && (!isY);

            float sx = fminf(fmaxf(psx, -s0), s0);
            float sy = fminf(fmaxf(psy, -s1), s1);
            float sz = fminf(fmaxf(psz, -s2), s2);
            sx = isX ? ((nix > 0.f) ? s0 : -s0) : sx;
            sy = isY ? ((niy > 0.f) ? s1 : -s1) : sy;
            sz = isZ ? ((niz > 0.f) ? s2 : -s2) : sz;

            // log2-space superquadric point
            const float hx  = sx*sx + sy*sy;
            const float r3  = hx + sz*sz;
            const float Lhx = flog2(hx);
            const float Lr3 = flog2(r3);
            const float Lx  = flog2(fabsf(sx));
            const float Ly  = flog2(fabsf(sy));
            const float Lz  = flog2(fabsf(sz));

            const float e0Lc = e0 * (0.5f*(Lhx - Lr3));
            const float aXe = fmaf(e1, fmaf(-0.5f, Lhx, Lx), e0Lc);
            const float aYe = fmaf(e1, fmaf(-0.5f, Lhx, Ly), e0Lc);
            const float aZe = e0 * fmaf(-0.5f, Lr3, Lz);

            const float X = copysignf(s0 * fexp2(aXe), sx);
            const float Y = copysignf(s1 * fexp2(aYe), sy);
            const float Z = copysignf(s2 * fexp2(aZe), sz);

            const float ddx = X-pcx, ddy = Y-pcy, ddz = Z-pcz;
            const float d2 = ddx*ddx + ddy*ddy + ddz*ddz;
            if (p) recB = fmaf(d2, ak, recB); else recA = fmaf(d2, ak, recA);
        }
    }

    // block-reduce rec (both points together)
    float rec = recA + recB;
    #pragma unroll
    for (int o = 32; o; o >>= 1) rec += __shfl_xor(rec, o);
    if (lane == 0) wsum[wave] = rec;

    // column-sum partials (both points together)
    #pragma unroll
    for (int kk = 0; kk < KPT; ++kk) {
        float v = aA[kk] + aB[kk];
        #pragma unroll
        for (int o = 32; o; o >>= 1) v += __shfl_xor(v, o);
        if (lane == 0) csum[wave][kk] = v;
    }
    __syncthreads();
    if (t == 0) recpart[bid] = wsum[0] + wsum[1] + wsum[2] + wsum[3];
    if (t < KPT) colpart[bid*KPT + t] = csum[0][t] + csum[1][t] + csum[2][t] + csum[3][t];
}

// Single block: column sums -> SPS/EXT; KLD; CST; REC sum; weighted combine.
__global__ __launch_bounds__(256) void finalize_kernel(
    const float* __restrict__ exist, const float* __restrict__ mu,
    const float* __restrict__ logvar, const float* __restrict__ mean,
    const float* __restrict__ trans, const float* __restrict__ recpart,
    const float* __restrict__ colpart, float* __restrict__ out)
{
    const int t = threadIdx.x;
    __shared__ float scol[NB*NK];
    __shared__ double red[256];

    // colsum[b][k] = sum over 8 chunks
    for (int i = t; i < NB*NK; i += 256) {
        int b = i >> 4, k = i & 15;
        float s = 0.f;
        #pragma unroll
        for (int c = 0; c < NCHUNK; ++c)
            s += colpart[(((b*NCHUNK + c)*NKG) + (k >> 2))*KPT + (k & 3)];
        scol[i] = s;
    }
    __syncthreads();

    double acc = 0.0;

    // KLD: native exp2 (e^x = 2^(x*log2e))
    for (int i = t; i < NB*ND; i += 256) {
        float lv = logvar[i], m = mu[i];
        float elv = fexp2(lv * 1.44269504f);
        acc += (double)(-0.5f * (1.0f + lv - m*m - elv)) * (W_KLD / (double)NB);
    }

    // EXT + CST over 512 (b,k) slots
    for (int i = t; i < NB*NK; i += 256) {
        float l  = exist[i];
        float gt = (scol[i] > 24.0f) ? 1.0f : 0.0f;
        float u  = fexp2(-fabsf(l) * 1.44269504f);
        float lg = flog2(1.0f + u) * 0.69314718f;
        float ext = fmaxf(l, 0.f) - l*gt + lg;
        acc += (double)ext * (W_EXT / (double)(NB*NK));

        float dx = mean[i*3+0] - trans[i*3+0];
        float dy = mean[i*3+1] - trans[i*3+1];
        float dz = mean[i*3+2] - trans[i*3+2];
        acc += (double)sqrtf(dx*dx + dy*dy + dz*dz) * (W_CST / (double)(NB*NK));
    }

    // REC over 1024 block partials
    for (int i = t; i < NBLK; i += 256)
        acc += (double)recpart[i] * (W_REC / ((double)NB * (double)NN));

    // SPS
    if (t < NB) {
        float sm = 0.f;
        #pragma unroll
        for (int k = 0; k < NK; ++k)
            sm += sqrtf(scol[t*NK + k] * (1.0f/(float)NN) + 0.01f);
        sm *= (1.0f/(float)NK);
        acc += (double)(sm*sm) * (W_SPS / (double)NB);
    }

    red[t] = acc;
    __syncthreads();
    for (int s2 = 128; s2; s2 >>= 1) {
        if (t < s2) red[t] += red[t + s2];
        __syncthreads();
    }
    if (t == 0) out[0] = (float)red[0];
}

extern "C" void kernel_launch(void* const* d_in, const int* in_sizes, int n_in,
                              void* d_out, int out_size, void* d_ws, size_t ws_size,
                              hipStream_t stream) {
    const float* pc      = (const float*)d_in[0];
    const float* normals = (const float*)d_in[1];
    const float* rnd     = (const float*)d_in[2];
    const float* scale   = (const float*)d_in[3];
    const float* shapes  = (const float*)d_in[4];
    const float* rotate  = (const float*)d_in[5];
    const float* mean    = (const float*)d_in[6];
    const float* assign  = (const float*)d_in[7];
    const float* exist   = (const float*)d_in[8];
    const float* mu      = (const float*)d_in[9];
    const float* logvar  = (const float*)d_in[10];
    const float* trans   = (const float*)d_in[11];

    float* recpart = (float*)d_ws;            // NBLK floats, all written each call
    float* colpart = recpart + NBLK;          // NBLK*KPT floats, all written each call

    rec_kernel<<<dim3(NBLK), dim3(256), 0, stream>>>(
        pc, normals, rnd, scale, shapes, rotate, mean, assign, recpart, colpart);
    finalize_kernel<<<dim3(1), dim3(256), 0, stream>>>(
        exist, mu, logvar, mean, trans, recpart, colpart, (float*)d_out);
}